// Round 3
// baseline (636.364 us; speedup 1.0000x reference)
//
#include <hip/hip_runtime.h>

typedef __attribute__((ext_vector_type(8))) short bf16x8;
typedef __attribute__((ext_vector_type(8))) unsigned short u16x8;
typedef __attribute__((ext_vector_type(4))) float f32x4;
typedef __attribute__((ext_vector_type(2))) unsigned uint2v;

#define DEVINL __device__ __forceinline__

constexpr int TB = 2;        // batch
constexpr int TT = 4096;     // seq len
constexpr int TD = 512;      // model dim
constexpr int TH = 8;        // heads
constexpr int THD = 64;      // head dim
constexpr int TM = TB * TT;  // 8192 flattened rows

// fp32 -> bf16 round-to-nearest-even
DEVINL unsigned short f2b(float f) {
  unsigned u = __builtin_bit_cast(unsigned, f);
  u += 0x7FFFu + ((u >> 16) & 1u);
  return (unsigned short)(u >> 16);
}

// pack 2 f32 -> 2 bf16 in one dword (lo -> low16, hi -> high16), RNE
DEVINL unsigned cvtpk(float lo, float hi) {
  unsigned r;
  asm("v_cvt_pk_bf16_f32 %0, %1, %2" : "=v"(r) : "v"(lo), "v"(hi));
  return r;
}

// barrier that only waits LDS ops (global stores may stay in flight)
DEVINL void lgkm_barrier() {
  asm volatile("s_waitcnt lgkmcnt(0)" ::: "memory");
  __builtin_amdgcn_s_barrier();
  __builtin_amdgcn_sched_barrier(0);
}

// ---------------------------------------------------------------------------
// GEMM: Y = X[M][512] @ W[512][512]^T  (torch Linear).
// MODE 0: bf16 row-major. MODE 1: fp32 + bias. MODE 2: bf16 per-head
// transposed VT[b][h][d][T] via swapped mfma operands.
// ---------------------------------------------------------------------------
template<int MODE>
__global__ __launch_bounds__(256, 2)
void gemm_xwt(const float* __restrict__ X, const float* __restrict__ W,
              unsigned short* __restrict__ Yb, float* __restrict__ Yf,
              const float* __restrict__ bias)
{
  constexpr int K = TD, N = TD;
  __shared__ unsigned short As[128][72];
  __shared__ unsigned short Bs[128][72];

  const int t    = threadIdx.x;
  const int lane = t & 63, w = t >> 6;
  const int fr = lane & 15, fq = lane >> 4;
  const int wr = (w >> 1) * 64, wc = (w & 1) * 64;
  const int bm = blockIdx.x * 128, bn = blockIdx.y * 128;
  const int srow = t >> 1;
  const int skh  = (t & 1) * 32;

  f32x4 acc[4][4];
  #pragma unroll
  for (int i = 0; i < 4; ++i)
    #pragma unroll
    for (int j = 0; j < 4; ++j)
      acc[i][j] = f32x4{0.f, 0.f, 0.f, 0.f};

  for (int k0 = 0; k0 < K; k0 += 64) {
    const float* srcA = X + (size_t)(bm + srow) * K + k0 + skh;
    const float* srcB = W + (size_t)(bn + srow) * K + k0 + skh;
    #pragma unroll
    for (int i = 0; i < 4; ++i) {
      float4 a0 = ((const float4*)srcA)[2 * i];
      float4 a1 = ((const float4*)srcA)[2 * i + 1];
      u16x8 oa = {f2b(a0.x), f2b(a0.y), f2b(a0.z), f2b(a0.w),
                  f2b(a1.x), f2b(a1.y), f2b(a1.z), f2b(a1.w)};
      *(u16x8*)&As[srow][skh + i * 8] = oa;
      float4 b0 = ((const float4*)srcB)[2 * i];
      float4 b1 = ((const float4*)srcB)[2 * i + 1];
      u16x8 ob = {f2b(b0.x), f2b(b0.y), f2b(b0.z), f2b(b0.w),
                  f2b(b1.x), f2b(b1.y), f2b(b1.z), f2b(b1.w)};
      *(u16x8*)&Bs[srow][skh + i * 8] = ob;
    }
    __syncthreads();
    #pragma unroll
    for (int kk = 0; kk < 2; ++kk) {
      bf16x8 af[4], bfv[4];
      #pragma unroll
      for (int i = 0; i < 4; ++i)
        af[i] = *(const bf16x8*)&As[wr + i * 16 + fr][kk * 32 + fq * 8];
      #pragma unroll
      for (int j = 0; j < 4; ++j)
        bfv[j] = *(const bf16x8*)&Bs[wc + j * 16 + fr][kk * 32 + fq * 8];
      #pragma unroll
      for (int i = 0; i < 4; ++i)
        #pragma unroll
        for (int j = 0; j < 4; ++j) {
          if (MODE == 2)
            acc[i][j] = __builtin_amdgcn_mfma_f32_16x16x32_bf16(bfv[i], af[j], acc[i][j], 0, 0, 0);
          else
            acc[i][j] = __builtin_amdgcn_mfma_f32_16x16x32_bf16(af[i], bfv[j], acc[i][j], 0, 0, 0);
        }
    }
    __syncthreads();
  }

  #pragma unroll
  for (int i = 0; i < 4; ++i) {
    #pragma unroll
    for (int j = 0; j < 4; ++j) {
      #pragma unroll
      for (int ii = 0; ii < 4; ++ii) {
        float v = acc[i][j][ii];
        if (MODE == 2) {
          const int Nidx = bn + wc + i * 16 + fq * 4 + ii;
          const int Midx = bm + wr + j * 16 + fr;
          const int h = Nidx >> 6, d = Nidx & (THD - 1);
          const int b = Midx >> 12, tt = Midx & (TT - 1);
          Yb[((size_t)(b * TH + h) * THD + d) * TT + tt] = f2b(v);
        } else {
          const int gm = bm + wr + i * 16 + fq * 4 + ii;
          const int gn = bn + wc + j * 16 + fr;
          if (MODE == 1) Yf[(size_t)gm * N + gn] = v + bias[gn];
          else           Yb[(size_t)gm * N + gn] = f2b(v);
        }
      }
    }
  }
}

// ---------------------------------------------------------------------------
// Fused attention per (b,h,qblock=128): S = K Q^T (swapped operands -> per
// lane 4 consecutive kv in regs). Softmax without max-sub (|s|<~2).
// Pass1: row denominators. Pass2: p = exp2(s*K2 + log2(1/lsum)), float4
// nontemporal attn stores, P->LDS via cvt_pk+b64, PV accumulate.
// 8 waves x 16 q-rows; KV tiles 64, double-buffered. One resident round.
// ---------------------------------------------------------------------------
__global__ __launch_bounds__(512, 4)
void attn_fused(const unsigned short* __restrict__ Qb,
                const unsigned short* __restrict__ Kb,
                const unsigned short* __restrict__ VTg,
                float* __restrict__ attnO, float* __restrict__ Z)
{
  __shared__ unsigned short Ks[2][64][72];     // 18.4 KB  K rows [kv][d]
  __shared__ unsigned short VTs[2][64][72];    // 18.4 KB  V^T rows [d][kv]
  __shared__ unsigned short Ps[8][16][72];     // 18.4 KB  per-wave P [q][kv]

  const int t    = threadIdx.x;
  const int lane = t & 63, w = t >> 6;         // w = 0..7
  const int fr = lane & 15, fq = lane >> 4;
  const int bh = blockIdx.y;                   // b*8+h
  const int b  = bh >> 3, h = bh & 7;
  const int q0 = blockIdx.x * 128;

  const size_t rowKV  = ((size_t)(b * TT)) * TD + h * THD;
  const size_t vtBase = (size_t)bh * THD * TT;

  const int tr = t >> 3;           // 0..63 staging row
  const int tc = (t & 7) * 8;      // col (x8 elems = 16B)

  auto loadK = [&](int kv0, u16x8& r) {
    r = *(const u16x8*)(Kb + rowKV + (size_t)(kv0 + tr) * TD + tc);
  };
  auto loadVT = [&](int kv0, u16x8& r) {
    r = *(const u16x8*)(VTg + vtBase + (size_t)tr * TT + kv0 + tc);
  };
  auto writeK  = [&](int buf, const u16x8& r) { *(u16x8*)&Ks[buf][tr][tc]  = r; };
  auto writeVT = [&](int buf, const u16x8& r) { *(u16x8*)&VTs[buf][tr][tc] = r; };

  // Q fragments: per-lane direct global load (B-operand; row = q = w*16+fr)
  const unsigned short* qsrc = Qb + ((size_t)(b * TT + q0 + w * 16 + fr)) * TD + h * THD;
  bf16x8 aq[2];
  aq[0] = *(const bf16x8*)(qsrc + fq * 8);
  aq[1] = *(const bf16x8*)(qsrc + 32 + fq * 8);

  constexpr int NT = TT / 64;                     // 64 kv tiles
  constexpr float K2 = 0.18033688011112042f;      // (1/8) * log2(e)

  u16x8 kr, vr;
  loadK(0, kr);
  writeK(0, kr);
  lgkm_barrier();

  // ---- pass 1: row sums of exp(s/8) ----
  float lsum = 0.f;
  for (int j = 0; j < NT; ++j) {
    const int cur = j & 1;
    if (j + 1 < NT) loadK((j + 1) * 64, kr);
    __builtin_amdgcn_s_setprio(1);
    #pragma unroll
    for (int n = 0; n < 4; ++n) {
      f32x4 s = f32x4{0.f, 0.f, 0.f, 0.f};
      #pragma unroll
      for (int kk = 0; kk < 2; ++kk) {
        bf16x8 ak = *(const bf16x8*)&Ks[cur][n * 16 + fr][kk * 32 + fq * 8];
        s = __builtin_amdgcn_mfma_f32_16x16x32_bf16(ak, aq[kk], s, 0, 0, 0);
      }
      #pragma unroll
      for (int i = 0; i < 4; ++i)
        lsum += __builtin_amdgcn_exp2f(s[i] * K2);
    }
    __builtin_amdgcn_s_setprio(0);
    if (j + 1 < NT) writeK(cur ^ 1, kr);
    lgkm_barrier();
  }
  // kv spread across fq groups; q is lane-local -> reduce over fq only
  lsum += __shfl_xor(lsum, 16, 64);
  lsum += __shfl_xor(lsum, 32, 64);
  const float l2i = -__log2f(lsum);    // log2(1/lsum)

  // ---- pass 2: recompute, write attn, accumulate PV ----
  loadK(0, kr);
  loadVT(0, vr);
  writeK(0, kr);
  writeVT(0, vr);
  lgkm_barrier();

  f32x4 accz[4];
  #pragma unroll
  for (int n = 0; n < 4; ++n) accz[n] = f32x4{0.f, 0.f, 0.f, 0.f};

  // attn row for this lane: q = q0 + w*16 + fr; within row: kv0 + n*16 + fq*4
  float* arow = attnO + ((size_t)bh * TT + q0 + w * 16 + fr) * TT + fq * 4;

  for (int j = 0; j < NT; ++j) {
    const int cur = j & 1;
    const int kv0 = j * 64;
    if (j + 1 < NT) {
      loadK((j + 1) * 64, kr);
      loadVT((j + 1) * 64, vr);
    }
    // QK^T (swapped): s[n][i] = S[kv = kv0+n*16+fq*4+i][q = q0+w*16+fr]
    f32x4 sv[4];
    __builtin_amdgcn_s_setprio(1);
    #pragma unroll
    for (int n = 0; n < 4; ++n) {
      f32x4 s = f32x4{0.f, 0.f, 0.f, 0.f};
      #pragma unroll
      for (int kk = 0; kk < 2; ++kk) {
        bf16x8 ak = *(const bf16x8*)&Ks[cur][n * 16 + fr][kk * 32 + fq * 8];
        s = __builtin_amdgcn_mfma_f32_16x16x32_bf16(ak, aq[kk], s, 0, 0, 0);
      }
      sv[n] = s;
    }
    __builtin_amdgcn_s_setprio(0);
    // p = exp2(s*K2 + log2(1/lsum))  (normalized attention value)
    float p[4][4];
    #pragma unroll
    for (int n = 0; n < 4; ++n)
      #pragma unroll
      for (int i = 0; i < 4; ++i)
        p[n][i] = __builtin_amdgcn_exp2f(fmaf(sv[n][i], K2, l2i));
    // stores back-to-back for write combining (4 x float4 per lane)
    #pragma unroll
    for (int n = 0; n < 4; ++n) {
      f32x4 pv4 = {p[n][0], p[n][1], p[n][2], p[n][3]};
      __builtin_nontemporal_store(pv4, (f32x4*)(arow + kv0 + n * 16));
    }
    // P -> LDS (bf16) for PV A-fragments: Ps[q][kv]
    #pragma unroll
    for (int n = 0; n < 4; ++n) {
      uint2v u = {cvtpk(p[n][0], p[n][1]), cvtpk(p[n][2], p[n][3])};
      *(uint2v*)&Ps[w][fr][n * 16 + fq * 4] = u;
    }
    // wave-local: Ps writes + K reads must land before P reads
    asm volatile("s_waitcnt lgkmcnt(0)" ::: "memory");
    __builtin_amdgcn_sched_barrier(0);
    __builtin_amdgcn_s_setprio(1);
    #pragma unroll
    for (int kk = 0; kk < 2; ++kk) {
      bf16x8 ap = *(const bf16x8*)&Ps[w][fr][kk * 32 + fq * 8];
      #pragma unroll
      for (int n = 0; n < 4; ++n) {
        bf16x8 bv = *(const bf16x8*)&VTs[cur][n * 16 + fr][kk * 32 + fq * 8];
        accz[n] = __builtin_amdgcn_mfma_f32_16x16x32_bf16(ap, bv, accz[n], 0, 0, 0);
      }
    }
    __builtin_amdgcn_s_setprio(0);
    if (j + 1 < NT) {
      writeK(cur ^ 1, kr);
      writeVT(cur ^ 1, vr);
    }
    lgkm_barrier();
  }

  // Z in [B*T, D] layout; accz[n][i] = Z[q=q0+w*16+fq*4+i][d=n*16+fr]
  const size_t zbase = ((size_t)(b * TT + q0 + w * 16 + fq * 4)) * TD + h * THD + fr;
  #pragma unroll
  for (int n = 0; n < 4; ++n)
    #pragma unroll
    for (int i = 0; i < 4; ++i)
      Z[zbase + (size_t)i * TD + n * 16] = accz[n][i];
}

// ---------------------------------------------------------------------------
extern "C" void kernel_launch(void* const* d_in, const int* in_sizes, int n_in,
                              void* d_out, int out_size, void* d_ws, size_t ws_size,
                              hipStream_t stream) {
  const float* queries = (const float*)d_in[0];
  const float* keys    = (const float*)d_in[1];
  const float* values  = (const float*)d_in[2];
  const float* Wq = (const float*)d_in[3];
  const float* Wk = (const float*)d_in[4];
  const float* Wv = (const float*)d_in[5];
  const float* Wo = (const float*)d_in[6];
  const float* bo = (const float*)d_in[7];

  float* out  = (float*)d_out;                       // [2,4096,512]
  float* attn = out + (size_t)TM * TD;               // [2,8,4096,4096]

  unsigned short* qb = (unsigned short*)d_ws;
  unsigned short* kb = qb + (size_t)TM * TD;
  unsigned short* vt = kb + (size_t)TM * TD;
  float*          zf = (float*)(vt + (size_t)TM * TD);

  dim3 gg(TM / 128, TD / 128), bb(256);
  gemm_xwt<0><<<gg, bb, 0, stream>>>(queries, Wq, qb, nullptr, nullptr);
  gemm_xwt<0><<<gg, bb, 0, stream>>>(keys,    Wk, kb, nullptr, nullptr);
  gemm_xwt<2><<<gg, bb, 0, stream>>>(values,  Wv, vt, nullptr, nullptr);

  attn_fused<<<dim3(TT / 128, TB * TH), dim3(512), 0, stream>>>(qb, kb, vt, attn, zf);

  gemm_xwt<1><<<gg, bb, 0, stream>>>(zf, Wo, nullptr, out, bo);
}

// Round 4
// 534.439 us; speedup vs baseline: 1.1907x; 1.1907x over previous
//
#include <hip/hip_runtime.h>

typedef __attribute__((ext_vector_type(8))) short bf16x8;
typedef __attribute__((ext_vector_type(8))) unsigned short u16x8;
typedef __attribute__((ext_vector_type(4))) float f32x4;
typedef __attribute__((ext_vector_type(2))) unsigned uint2v;

#define DEVINL __device__ __forceinline__

constexpr int TB = 2;        // batch
constexpr int TT = 4096;     // seq len
constexpr int TD = 512;      // model dim
constexpr int TH = 8;        // heads
constexpr int THD = 64;      // head dim
constexpr int TM = TB * TT;  // 8192 flattened rows

// fp32 -> bf16 round-to-nearest-even
DEVINL unsigned short f2b(float f) {
  unsigned u = __builtin_bit_cast(unsigned, f);
  u += 0x7FFFu + ((u >> 16) & 1u);
  return (unsigned short)(u >> 16);
}

// pack 2 f32 -> 2 bf16 in one dword (lo -> low16, hi -> high16), RNE
DEVINL unsigned cvtpk(float lo, float hi) {
  unsigned r;
  asm("v_cvt_pk_bf16_f32 %0, %1, %2" : "=v"(r) : "v"(lo), "v"(hi));
  return r;
}

// barrier that only waits LDS ops (global stores may stay in flight)
DEVINL void lgkm_barrier() {
  asm volatile("s_waitcnt lgkmcnt(0)" ::: "memory");
  __builtin_amdgcn_s_barrier();
  __builtin_amdgcn_sched_barrier(0);
}

// ---------------------------------------------------------------------------
// GEMM: Y = X[M][512] @ W[512][512]^T  (torch Linear).
// MODE 0: bf16 row-major. MODE 1: fp32 + bias. MODE 2: bf16 per-head
// transposed VT[b][h][d][T] via swapped mfma operands.
// ---------------------------------------------------------------------------
template<int MODE>
__global__ __launch_bounds__(256, 2)
void gemm_xwt(const float* __restrict__ X, const float* __restrict__ W,
              unsigned short* __restrict__ Yb, float* __restrict__ Yf,
              const float* __restrict__ bias)
{
  constexpr int K = TD, N = TD;
  __shared__ unsigned short As[128][72];
  __shared__ unsigned short Bs[128][72];

  const int t    = threadIdx.x;
  const int lane = t & 63, w = t >> 6;
  const int fr = lane & 15, fq = lane >> 4;
  const int wr = (w >> 1) * 64, wc = (w & 1) * 64;
  const int bm = blockIdx.x * 128, bn = blockIdx.y * 128;
  const int srow = t >> 1;
  const int skh  = (t & 1) * 32;

  f32x4 acc[4][4];
  #pragma unroll
  for (int i = 0; i < 4; ++i)
    #pragma unroll
    for (int j = 0; j < 4; ++j)
      acc[i][j] = f32x4{0.f, 0.f, 0.f, 0.f};

  for (int k0 = 0; k0 < K; k0 += 64) {
    const float* srcA = X + (size_t)(bm + srow) * K + k0 + skh;
    const float* srcB = W + (size_t)(bn + srow) * K + k0 + skh;
    #pragma unroll
    for (int i = 0; i < 4; ++i) {
      float4 a0 = ((const float4*)srcA)[2 * i];
      float4 a1 = ((const float4*)srcA)[2 * i + 1];
      u16x8 oa = {f2b(a0.x), f2b(a0.y), f2b(a0.z), f2b(a0.w),
                  f2b(a1.x), f2b(a1.y), f2b(a1.z), f2b(a1.w)};
      *(u16x8*)&As[srow][skh + i * 8] = oa;
      float4 b0 = ((const float4*)srcB)[2 * i];
      float4 b1 = ((const float4*)srcB)[2 * i + 1];
      u16x8 ob = {f2b(b0.x), f2b(b0.y), f2b(b0.z), f2b(b0.w),
                  f2b(b1.x), f2b(b1.y), f2b(b1.z), f2b(b1.w)};
      *(u16x8*)&Bs[srow][skh + i * 8] = ob;
    }
    __syncthreads();
    #pragma unroll
    for (int kk = 0; kk < 2; ++kk) {
      bf16x8 af[4], bfv[4];
      #pragma unroll
      for (int i = 0; i < 4; ++i)
        af[i] = *(const bf16x8*)&As[wr + i * 16 + fr][kk * 32 + fq * 8];
      #pragma unroll
      for (int j = 0; j < 4; ++j)
        bfv[j] = *(const bf16x8*)&Bs[wc + j * 16 + fr][kk * 32 + fq * 8];
      #pragma unroll
      for (int i = 0; i < 4; ++i)
        #pragma unroll
        for (int j = 0; j < 4; ++j) {
          if (MODE == 2)
            acc[i][j] = __builtin_amdgcn_mfma_f32_16x16x32_bf16(bfv[i], af[j], acc[i][j], 0, 0, 0);
          else
            acc[i][j] = __builtin_amdgcn_mfma_f32_16x16x32_bf16(af[i], bfv[j], acc[i][j], 0, 0, 0);
        }
    }
    __syncthreads();
  }

  #pragma unroll
  for (int i = 0; i < 4; ++i) {
    #pragma unroll
    for (int j = 0; j < 4; ++j) {
      #pragma unroll
      for (int ii = 0; ii < 4; ++ii) {
        float v = acc[i][j][ii];
        if (MODE == 2) {
          const int Nidx = bn + wc + i * 16 + fq * 4 + ii;
          const int Midx = bm + wr + j * 16 + fr;
          const int h = Nidx >> 6, d = Nidx & (THD - 1);
          const int b = Midx >> 12, tt = Midx & (TT - 1);
          Yb[((size_t)(b * TH + h) * THD + d) * TT + tt] = f2b(v);
        } else {
          const int gm = bm + wr + i * 16 + fq * 4 + ii;
          const int gn = bn + wc + j * 16 + fr;
          if (MODE == 1) Yf[(size_t)gm * N + gn] = v + bias[gn];
          else           Yb[(size_t)gm * N + gn] = f2b(v);
        }
      }
    }
  }
}

// ---------------------------------------------------------------------------
// Fused attention per (b,h,qblock=64): S = K Q^T (swapped operands -> per
// lane 4 consecutive kv in regs; q is lane-local). No max-sub (|s|<~2).
// Pass1: row denominators (2-shuffle reduce). Pass2: p = exp2(s*K2 + l2i),
// float4 NT attn stores, P->LDS via cvt_pk b64, PV accumulate.
// 4 waves x 16 q-rows; KV tiles 64, double-buffered. Round-2 occupancy shape:
// 256 thr, launch_bounds(256,2) (256-VGPR cap -> no spill), 46 KB LDS.
// ---------------------------------------------------------------------------
__global__ __launch_bounds__(256, 2)
void attn_fused(const unsigned short* __restrict__ Qb,
                const unsigned short* __restrict__ Kb,
                const unsigned short* __restrict__ VTg,
                float* __restrict__ attnO, float* __restrict__ Z)
{
  __shared__ unsigned short Ks[2][64][72];     // 18.4 KB  K rows [kv][d]
  __shared__ unsigned short VTs[2][64][72];    // 18.4 KB  V^T rows [d][kv]
  __shared__ unsigned short Ps[4][16][72];     // 9.2 KB   per-wave P [q][kv]

  const int t    = threadIdx.x;
  const int lane = t & 63, w = t >> 6;         // w = 0..3
  const int fr = lane & 15, fq = lane >> 4;
  const int bh = blockIdx.y;                   // b*8+h
  const int b  = bh >> 3, h = bh & 7;
  const int q0 = blockIdx.x * 64;

  const size_t rowKV  = ((size_t)(b * TT)) * TD + h * THD;
  const size_t vtBase = (size_t)bh * THD * TT;

  const int tr = t >> 2;           // 0..63 staging row
  const int tc = (t & 3) * 16;     // 0,16,32,48

  auto loadK = [&](int kv0, u16x8& r0, u16x8& r1) {
    const unsigned short* src = Kb + rowKV + (size_t)(kv0 + tr) * TD + tc;
    r0 = *(const u16x8*)src;
    r1 = *(const u16x8*)(src + 8);
  };
  auto loadVT = [&](int kv0, u16x8& r0, u16x8& r1) {
    const unsigned short* src = VTg + vtBase + (size_t)tr * TT + kv0 + tc;
    r0 = *(const u16x8*)src;
    r1 = *(const u16x8*)(src + 8);
  };
  auto writeK = [&](int buf, const u16x8& r0, const u16x8& r1) {
    *(u16x8*)&Ks[buf][tr][tc]     = r0;
    *(u16x8*)&Ks[buf][tr][tc + 8] = r1;
  };
  auto writeVT = [&](int buf, const u16x8& r0, const u16x8& r1) {
    *(u16x8*)&VTs[buf][tr][tc]     = r0;
    *(u16x8*)&VTs[buf][tr][tc + 8] = r1;
  };

  // Q held in registers (B-operand of swapped QK; row = q = w*16+fr)
  const unsigned short* qsrc = Qb + ((size_t)(b * TT + q0 + w * 16 + fr)) * TD + h * THD;
  bf16x8 aq[2];
  aq[0] = *(const bf16x8*)(qsrc + fq * 8);
  aq[1] = *(const bf16x8*)(qsrc + 32 + fq * 8);

  constexpr int NT = TT / 64;                     // 64 kv tiles
  constexpr float K2 = 0.18033688011112042f;      // (1/8) * log2(e)

  u16x8 kr0, kr1, vr0, vr1;
  loadK(0, kr0, kr1);
  writeK(0, kr0, kr1);
  lgkm_barrier();

  // ---- pass 1: row sums of exp(s/8) ----
  float lsum = 0.f;
  for (int j = 0; j < NT; ++j) {
    const int cur = j & 1;
    if (j + 1 < NT) loadK((j + 1) * 64, kr0, kr1);
    __builtin_amdgcn_s_setprio(1);
    #pragma unroll
    for (int n = 0; n < 4; ++n) {
      f32x4 s = f32x4{0.f, 0.f, 0.f, 0.f};
      #pragma unroll
      for (int kk = 0; kk < 2; ++kk) {
        bf16x8 ak = *(const bf16x8*)&Ks[cur][n * 16 + fr][kk * 32 + fq * 8];
        s = __builtin_amdgcn_mfma_f32_16x16x32_bf16(ak, aq[kk], s, 0, 0, 0);
      }
      #pragma unroll
      for (int i = 0; i < 4; ++i)
        lsum += __builtin_amdgcn_exp2f(s[i] * K2);
    }
    __builtin_amdgcn_s_setprio(0);
    if (j + 1 < NT) writeK(cur ^ 1, kr0, kr1);
    lgkm_barrier();
  }
  // kv spread across fq groups; q is lane-local -> reduce over fq only
  lsum += __shfl_xor(lsum, 16, 64);
  lsum += __shfl_xor(lsum, 32, 64);
  const float l2i = -__log2f(lsum);    // log2(1/lsum)

  // ---- pass 2: recompute, write attn, accumulate PV ----
  loadK(0, kr0, kr1);
  loadVT(0, vr0, vr1);
  writeK(0, kr0, kr1);
  writeVT(0, vr0, vr1);
  lgkm_barrier();

  f32x4 accz[4];
  #pragma unroll
  for (int n = 0; n < 4; ++n) accz[n] = f32x4{0.f, 0.f, 0.f, 0.f};

  // attn row for this lane: q = q0 + w*16 + fr; within row: kv0 + n*16 + fq*4
  float* arow = attnO + ((size_t)bh * TT + q0 + w * 16 + fr) * TT + fq * 4;

  for (int j = 0; j < NT; ++j) {
    const int cur = j & 1;
    const int kv0 = j * 64;
    if (j + 1 < NT) {
      loadK((j + 1) * 64, kr0, kr1);
      loadVT((j + 1) * 64, vr0, vr1);
    }
    // QK^T (swapped): s[n][i] = S[kv = kv0+n*16+fq*4+i][q = q0+w*16+fr]
    f32x4 sv[4];
    __builtin_amdgcn_s_setprio(1);
    #pragma unroll
    for (int n = 0; n < 4; ++n) {
      f32x4 s = f32x4{0.f, 0.f, 0.f, 0.f};
      #pragma unroll
      for (int kk = 0; kk < 2; ++kk) {
        bf16x8 ak = *(const bf16x8*)&Ks[cur][n * 16 + fr][kk * 32 + fq * 8];
        s = __builtin_amdgcn_mfma_f32_16x16x32_bf16(ak, aq[kk], s, 0, 0, 0);
      }
      sv[n] = s;
    }
    __builtin_amdgcn_s_setprio(0);
    // p = exp2(s*K2 + log2(1/lsum))  (normalized attention value)
    float p[4][4];
    #pragma unroll
    for (int n = 0; n < 4; ++n)
      #pragma unroll
      for (int i = 0; i < 4; ++i)
        p[n][i] = __builtin_amdgcn_exp2f(fmaf(sv[n][i], K2, l2i));
    // 4 x float4 nontemporal stores (256B contiguous per row per tile)
    #pragma unroll
    for (int n = 0; n < 4; ++n) {
      f32x4 pv4 = {p[n][0], p[n][1], p[n][2], p[n][3]};
      __builtin_nontemporal_store(pv4, (f32x4*)(arow + kv0 + n * 16));
    }
    // P -> LDS (bf16) for PV A-fragments: Ps[q][kv]
    #pragma unroll
    for (int n = 0; n < 4; ++n) {
      uint2v u = {cvtpk(p[n][0], p[n][1]), cvtpk(p[n][2], p[n][3])};
      *(uint2v*)&Ps[w][fr][n * 16 + fq * 4] = u;
    }
    // wave-local: Ps writes must land before reading P as A-fragments
    asm volatile("s_waitcnt lgkmcnt(0)" ::: "memory");
    __builtin_amdgcn_sched_barrier(0);
    __builtin_amdgcn_s_setprio(1);
    #pragma unroll
    for (int kk = 0; kk < 2; ++kk) {
      bf16x8 ap = *(const bf16x8*)&Ps[w][fr][kk * 32 + fq * 8];
      #pragma unroll
      for (int n = 0; n < 4; ++n) {
        bf16x8 bv = *(const bf16x8*)&VTs[cur][n * 16 + fr][kk * 32 + fq * 8];
        accz[n] = __builtin_amdgcn_mfma_f32_16x16x32_bf16(ap, bv, accz[n], 0, 0, 0);
      }
    }
    __builtin_amdgcn_s_setprio(0);
    if (j + 1 < NT) {
      writeK(cur ^ 1, kr0, kr1);
      writeVT(cur ^ 1, vr0, vr1);
    }
    lgkm_barrier();
  }

  // Z in [B*T, D]; accz[n][i] = Z[q = q0+w*16+fq*4+i][d = n*16+fr]
  const size_t zbase = ((size_t)(b * TT + q0 + w * 16 + fq * 4)) * TD + h * THD + fr;
  #pragma unroll
  for (int n = 0; n < 4; ++n)
    #pragma unroll
    for (int i = 0; i < 4; ++i)
      Z[zbase + (size_t)i * TD + n * 16] = accz[n][i];
}

// ---------------------------------------------------------------------------
extern "C" void kernel_launch(void* const* d_in, const int* in_sizes, int n_in,
                              void* d_out, int out_size, void* d_ws, size_t ws_size,
                              hipStream_t stream) {
  const float* queries = (const float*)d_in[0];
  const float* keys    = (const float*)d_in[1];
  const float* values  = (const float*)d_in[2];
  const float* Wq = (const float*)d_in[3];
  const float* Wk = (const float*)d_in[4];
  const float* Wv = (const float*)d_in[5];
  const float* Wo = (const float*)d_in[6];
  const float* bo = (const float*)d_in[7];

  float* out  = (float*)d_out;                       // [2,4096,512]
  float* attn = out + (size_t)TM * TD;               // [2,8,4096,4096]

  unsigned short* qb = (unsigned short*)d_ws;
  unsigned short* kb = qb + (size_t)TM * TD;
  unsigned short* vt = kb + (size_t)TM * TD;
  float*          zf = (float*)(vt + (size_t)TM * TD);

  dim3 gg(TM / 128, TD / 128), bb(256);
  gemm_xwt<0><<<gg, bb, 0, stream>>>(queries, Wq, qb, nullptr, nullptr);
  gemm_xwt<0><<<gg, bb, 0, stream>>>(keys,    Wk, kb, nullptr, nullptr);
  gemm_xwt<2><<<gg, bb, 0, stream>>>(values,  Wv, vt, nullptr, nullptr);

  attn_fused<<<dim3(TT / 64, TB * TH), bb, 0, stream>>>(qb, kb, vt, attn, zf);

  gemm_xwt<1><<<gg, bb, 0, stream>>>(zf, Wo, nullptr, out, bo);
}